// Round 1
// baseline (616.585 us; speedup 1.0000x reference)
//
#include <hip/hip_runtime.h>

#define N_NODES 50000
#define N_EDGES 800000

// ---------------- graph preprocessing ----------------

__global__ void hist_kernel(const int* __restrict__ dst, int* __restrict__ deg, int E) {
    int e = blockIdx.x * blockDim.x + threadIdx.x;
    if (e < E) atomicAdd(&deg[dst[e]], 1);
}

__global__ void dinv_kernel(const int* __restrict__ deg, float* __restrict__ dinv, int n) {
    int i = blockIdx.x * blockDim.x + threadIdx.x;
    if (i < n) dinv[i] = rsqrtf((float)(deg[i] + 1));  // +1 self-loop; deg>=1 always
}

__device__ __forceinline__ int wave_incl_scan(int x) {
    int lane = threadIdx.x & 63;
#pragma unroll
    for (int off = 1; off < 64; off <<= 1) {
        int y = __shfl_up(x, off, 64);
        if (lane >= off) x += y;
    }
    return x;
}

// exclusive scan of a 512-element chunk; writes per-chunk exclusive partials + chunk total
__global__ void scan_partial(const int* __restrict__ in, int n,
                             int* __restrict__ out_partial, int* __restrict__ blocksum) {
    __shared__ int wsum[8];
    int i = blockIdx.x * 512 + threadIdx.x;
    int v = (i < n) ? in[i] : 0;
    int inc = wave_incl_scan(v);
    int lane = threadIdx.x & 63, wid = threadIdx.x >> 6;
    if (lane == 63) wsum[wid] = inc;
    __syncthreads();
    if (wid == 0) {
        int w = (lane < 8) ? wsum[lane] : 0;
        int wi = wave_incl_scan(w);
        if (lane < 8) wsum[lane] = wi;
    }
    __syncthreads();
    int woff = (wid == 0) ? 0 : wsum[wid - 1];
    if (i < n) out_partial[i] = woff + inc - v;
    if (threadIdx.x == 0) blocksum[blockIdx.x] = wsum[7];
}

// exclusive scan of up to 128 block sums (nb=98 here)
__global__ void scan_small(const int* __restrict__ in, int nb, int* __restrict__ out) {
    __shared__ int wsum[2];
    int i = threadIdx.x;
    int v = (i < nb) ? in[i] : 0;
    int inc = wave_incl_scan(v);
    int lane = threadIdx.x & 63, wid = threadIdx.x >> 6;
    if (lane == 63) wsum[wid] = inc;
    __syncthreads();
    int woff = (wid == 0) ? 0 : wsum[0];
    if (i < nb) out[i] = woff + inc - v;
}

__global__ void scan_add(int* __restrict__ rowptr, int n, const int* __restrict__ blockoff, int total) {
    int i = blockIdx.x * 512 + threadIdx.x;
    if (i < n) rowptr[i] += blockoff[blockIdx.x];
    if (i == 0) rowptr[n] = total;
}

__global__ void fill_csr(const int* __restrict__ src, const int* __restrict__ dst, int E,
                         const int* __restrict__ rowptr, int* __restrict__ cursor,
                         int* __restrict__ csr_src) {
    int e = blockIdx.x * blockDim.x + threadIdx.x;
    if (e < E) {
        int d = dst[e];
        int pos = rowptr[d] + atomicAdd(&cursor[d], 1);
        csr_src[pos] = src[e];
    }
}

// ---------------- aggregation: out[i] = dinv[i]*( dinv[i]*in[i] + sum_e dinv[s]*in[s] ) ----------------

template <int F>
__global__ void aggregate_kernel(const float* __restrict__ in, float* __restrict__ out,
                                 const int* __restrict__ rowptr, const int* __restrict__ csr_src,
                                 const float* __restrict__ dinv) {
    int node = blockIdx.x;
    int f = threadIdx.x;
    int beg = rowptr[node], end = rowptr[node + 1];
    float di = dinv[node];
    float acc = di * in[(size_t)node * F + f];  // self-loop (x dinv[i] again below)
    for (int e = beg; e < end; ++e) {
        int s = csr_src[e];
        acc += dinv[s] * in[(size_t)s * F + f];
    }
    out[(size_t)node * F + f] = di * acc;
}

// ---------------- simple tiled f32 GEMM: C = A[MxK] * B[KxN] (+bias)(+C)(relu) ----------------

template <bool BIAS, bool RELU, bool ACCUM>
__global__ __launch_bounds__(256) void gemm_kernel(const float* __restrict__ A, const float* __restrict__ B,
                                                   const float* __restrict__ bias, float* __restrict__ C,
                                                   int M, int N, int K) {
    __shared__ float As[16][65];  // padded: avoid 16-way bank conflict on transposed store
    __shared__ float Bs[16][64];
    const int tid = threadIdx.x;
    const int tx = tid & 15, ty = tid >> 4;
    const int row0 = blockIdx.x * 64, col0 = blockIdx.y * 64;
    float acc[4][4] = {};
    for (int k0 = 0; k0 < K; k0 += 16) {
#pragma unroll
        for (int i = tid; i < 64 * 16; i += 256) {
            int r = i >> 4, kk = i & 15;
            int gr = row0 + r;
            As[kk][r] = (gr < M) ? A[(size_t)gr * K + k0 + kk] : 0.f;
        }
#pragma unroll
        for (int i = tid; i < 16 * 64; i += 256) {
            int kk = i >> 6, c = i & 63;
            Bs[kk][c] = B[(size_t)(k0 + kk) * N + col0 + c];
        }
        __syncthreads();
#pragma unroll
        for (int kk = 0; kk < 16; ++kk) {
            float a[4], b[4];
#pragma unroll
            for (int i = 0; i < 4; ++i) a[i] = As[kk][ty * 4 + i];
#pragma unroll
            for (int j = 0; j < 4; ++j) b[j] = Bs[kk][tx * 4 + j];
#pragma unroll
            for (int i = 0; i < 4; ++i)
#pragma unroll
                for (int j = 0; j < 4; ++j) acc[i][j] += a[i] * b[j];
        }
        __syncthreads();
    }
#pragma unroll
    for (int i = 0; i < 4; ++i) {
        int gr = row0 + ty * 4 + i;
        if (gr >= M) continue;
#pragma unroll
        for (int j = 0; j < 4; ++j) {
            int gc = col0 + tx * 4 + j;
            float v = acc[i][j];
            if (BIAS) v += bias[gc];
            if (ACCUM) v += C[(size_t)gr * N + gc];
            if (RELU) v = fmaxf(v, 0.f);
            C[(size_t)gr * N + gc] = v;
        }
    }
}

// ---------------- launch ----------------

extern "C" void kernel_launch(void* const* d_in, const int* in_sizes, int n_in,
                              void* d_out, int out_size, void* d_ws, size_t ws_size,
                              hipStream_t stream) {
    const float* x  = (const float*)d_in[0];
    const int*   ei = (const int*)d_in[1];
    const int*   src = ei;             // edge_index[0]
    const int*   dst = ei + N_EDGES;   // edge_index[1]
    const float* W1 = (const float*)d_in[2];
    const float* b1 = (const float*)d_in[3];
    const float* W2 = (const float*)d_in[4];
    const float* b2 = (const float*)d_in[5];
    const float* Wf = (const float*)d_in[6];
    const float* bf = (const float*)d_in[7];
    const float* Ws = (const float*)d_in[8];
    const float* bs = (const float*)d_in[9];
    float* out = (float*)d_out;

    char* ws = (char*)d_ws;
    size_t off = 0;
    auto alloc = [&](size_t bytes) -> void* {
        void* p = ws + off;
        off += (bytes + 255) & ~(size_t)255;
        return p;
    };
    int*   deg      = (int*)alloc(N_NODES * 4);
    int*   cursor   = (int*)alloc(N_NODES * 4);
    int*   rowptr   = (int*)alloc((N_NODES + 1) * 4);
    float* dinv     = (float*)alloc(N_NODES * 4);
    int*   blocksum = (int*)alloc(4096);
    int*   blockoff = (int*)alloc(4096);
    int*   csr      = (int*)alloc(N_EDGES * 4);
    float* bufA     = (float*)alloc((size_t)N_NODES * 256 * 4);
    float* bufB     = (float*)alloc((size_t)N_NODES * 256 * 4);

    hipMemsetAsync(deg, 0, N_NODES * 4, stream);
    hipMemsetAsync(cursor, 0, N_NODES * 4, stream);

    hist_kernel<<<(N_EDGES + 255) / 256, 256, 0, stream>>>(dst, deg, N_EDGES);
    dinv_kernel<<<(N_NODES + 255) / 256, 256, 0, stream>>>(deg, dinv, N_NODES);

    int nb = (N_NODES + 511) / 512;  // 98
    scan_partial<<<nb, 512, 0, stream>>>(deg, N_NODES, rowptr, blocksum);
    scan_small<<<1, 128, 0, stream>>>(blocksum, nb, blockoff);
    scan_add<<<nb, 512, 0, stream>>>(rowptr, N_NODES, blockoff, N_EDGES);
    fill_csr<<<(N_EDGES + 255) / 256, 256, 0, stream>>>(src, dst, N_EDGES, rowptr, cursor, csr);

    // layer 1: aggregate x (128-wide) then GEMM->256 with bias+relu
    aggregate_kernel<128><<<N_NODES, 128, 0, stream>>>(x, bufA, rowptr, csr, dinv);
    dim3 g1((N_NODES + 63) / 64, 256 / 64);
    gemm_kernel<true, true, false><<<g1, 256, 0, stream>>>(bufA, W1, b1, bufB, N_NODES, 256, 128);

    // layer 2: aggregate h1 (256-wide) then GEMM->256 with bias+relu
    aggregate_kernel<256><<<N_NODES, 256, 0, stream>>>(bufB, bufA, rowptr, csr, dinv);
    gemm_kernel<true, true, false><<<g1, 256, 0, stream>>>(bufA, W2, b2, bufB, N_NODES, 256, 256);

    // out = x@Ws + bs; out += h2@Wf + bf
    dim3 g2((N_NODES + 63) / 64, 1);
    gemm_kernel<true, false, false><<<g2, 256, 0, stream>>>(x, Ws, bs, out, N_NODES, 64, 128);
    gemm_kernel<true, false, true><<<g2, 256, 0, stream>>>(bufB, Wf, bf, out, N_NODES, 64, 256);
}

// Round 2
// 343.405 us; speedup vs baseline: 1.7955x; 1.7955x over previous
//
#include <hip/hip_runtime.h>

#define N_NODES 50000
#define N_EDGES 800000

typedef float f32x4 __attribute__((ext_vector_type(4)));
typedef __bf16 bf16x8 __attribute__((ext_vector_type(8)));
typedef __bf16 bf16x4 __attribute__((ext_vector_type(4)));
typedef __bf16 bf16x2 __attribute__((ext_vector_type(2)));

// ---------------- graph preprocessing ----------------

__global__ void hist_kernel(const int* __restrict__ dst, int* __restrict__ deg, int E) {
    int e = blockIdx.x * blockDim.x + threadIdx.x;
    if (e < E) atomicAdd(&deg[dst[e]], 1);
}

__global__ void dinv_kernel(const int* __restrict__ deg, float* __restrict__ dinv, int n) {
    int i = blockIdx.x * blockDim.x + threadIdx.x;
    if (i < n) dinv[i] = rsqrtf((float)(deg[i] + 1));  // +1 self-loop
}

__device__ __forceinline__ int wave_incl_scan(int x) {
    int lane = threadIdx.x & 63;
#pragma unroll
    for (int off = 1; off < 64; off <<= 1) {
        int y = __shfl_up(x, off, 64);
        if (lane >= off) x += y;
    }
    return x;
}

__global__ void scan_partial(const int* __restrict__ in, int n,
                             int* __restrict__ out_partial, int* __restrict__ blocksum) {
    __shared__ int wsum[8];
    int i = blockIdx.x * 512 + threadIdx.x;
    int v = (i < n) ? in[i] : 0;
    int inc = wave_incl_scan(v);
    int lane = threadIdx.x & 63, wid = threadIdx.x >> 6;
    if (lane == 63) wsum[wid] = inc;
    __syncthreads();
    if (wid == 0) {
        int w = (lane < 8) ? wsum[lane] : 0;
        int wi = wave_incl_scan(w);
        if (lane < 8) wsum[lane] = wi;
    }
    __syncthreads();
    int woff = (wid == 0) ? 0 : wsum[wid - 1];
    if (i < n) out_partial[i] = woff + inc - v;
    if (threadIdx.x == 0) blocksum[blockIdx.x] = wsum[7];
}

__global__ void scan_small(const int* __restrict__ in, int nb, int* __restrict__ out) {
    __shared__ int wsum[2];
    int i = threadIdx.x;
    int v = (i < nb) ? in[i] : 0;
    int inc = wave_incl_scan(v);
    int lane = threadIdx.x & 63, wid = threadIdx.x >> 6;
    if (lane == 63) wsum[wid] = inc;
    __syncthreads();
    int woff = (wid == 0) ? 0 : wsum[0];
    if (i < nb) out[i] = woff + inc - v;
}

__global__ void scan_add(int* __restrict__ rowptr, int n, const int* __restrict__ blockoff, int total) {
    int i = blockIdx.x * 512 + threadIdx.x;
    if (i < n) rowptr[i] += blockoff[blockIdx.x];
    if (i == 0) rowptr[n] = total;
}

__global__ void fill_csr(const int* __restrict__ src, const int* __restrict__ dst, int E,
                         const int* __restrict__ rowptr, int* __restrict__ cursor,
                         int* __restrict__ csr_src) {
    int e = blockIdx.x * blockDim.x + threadIdx.x;
    if (e < E) {
        int d = dst[e];
        int pos = rowptr[d] + atomicAdd(&cursor[d], 1);
        csr_src[pos] = src[e];
    }
}

// ---------------- casts / weight prep ----------------

__global__ void cast_bf16_kernel(const float* __restrict__ in, __bf16* __restrict__ out, int n4) {
    int i = blockIdx.x * blockDim.x + threadIdx.x;
    if (i < n4) {
        float4 v = ((const float4*)in)[i];
        bf16x4 o = {(__bf16)v.x, (__bf16)v.y, (__bf16)v.z, (__bf16)v.w};
        ((bf16x4*)out)[i] = o;
    }
}

// Wt[n*K + k] = (bf16) W[k*N + n]   (write-coalesced, tiny matrices)
__global__ void transpose_cast_kernel(const float* __restrict__ W, __bf16* __restrict__ Wt, int K, int N) {
    int idx = blockIdx.x * blockDim.x + threadIdx.x;
    if (idx < K * N) {
        int n = idx / K, k = idx - n * K;
        Wt[idx] = (__bf16)W[(size_t)k * N + n];
    }
}

__global__ void bias_add_kernel(const float* __restrict__ a, const float* __restrict__ b,
                                float* __restrict__ o, int n) {
    int i = blockIdx.x * blockDim.x + threadIdx.x;
    if (i < n) o[i] = a[i] + b[i];
}

// ---------------- aggregation (bf16): one wave per node ----------------

template <int V> struct VecSel;
template <> struct VecSel<2> { using T = bf16x2; };
template <> struct VecSel<4> { using T = bf16x4; };

template <int F>
__global__ __launch_bounds__(256) void aggregate_bf(const __bf16* __restrict__ in, __bf16* __restrict__ out,
                                                    const int* __restrict__ rowptr, const int* __restrict__ csr_src,
                                                    const float* __restrict__ dinv) {
    constexpr int V = F / 64;
    using VT = typename VecSel<V>::T;
    int node = blockIdx.x * 4 + (threadIdx.x >> 6);
    if (node >= N_NODES) return;
    int lane = threadIdx.x & 63;
    float di = dinv[node];
    VT sv = *(const VT*)(in + (size_t)node * F + lane * V);
    float acc[V];
#pragma unroll
    for (int j = 0; j < V; ++j) acc[j] = di * (float)sv[j];
    int beg = rowptr[node], end = rowptr[node + 1];
    for (int e = beg; e < end; ++e) {
        int s = csr_src[e];
        float w = dinv[s];
        VT v = *(const VT*)(in + (size_t)s * F + lane * V);
#pragma unroll
        for (int j = 0; j < V; ++j) acc[j] += w * (float)v[j];
    }
    VT o;
#pragma unroll
    for (int j = 0; j < V; ++j) o[j] = (__bf16)(di * acc[j]);
    *(VT*)(out + (size_t)node * F + lane * V) = o;
}

// ---------------- MFMA bf16 GEMM ----------------
// C[M x N] = A[M x K] * Bt[N x K]^T (+ optional second pair) + bias, opt relu.
// BM=128, BN=64, BK=64, 256 threads = 4 waves (2x2), wave tile 64x32.
// LDS layout: rows of 64 bf16 (128 B = 8 granules of 16 B), granule slot XOR-swizzled
// with (row&7). global_load_lds writes linearly; the global SOURCE address is
// pre-swizzled with the same involution so read-side swizzle matches (rule 21).

template <int NROWS>
__device__ __forceinline__ void stage_tile(const __bf16* __restrict__ src, int K, int row0, int rowclamp,
                                           int k0, char* lds) {
    int t = threadIdx.x;
#pragma unroll
    for (int p = 0; p < NROWS * 8 / 256; ++p) {
        int G = p * 256 + t;
        int r = G >> 3, gp = G & 7;
        int g = gp ^ (r & 7);
        int gr = row0 + r;
        if (gr > rowclamp) gr = rowclamp;
        const __bf16* sp = src + (size_t)gr * K + k0 + g * 8;
        __builtin_amdgcn_global_load_lds((const __attribute__((address_space(1))) void*)sp,
                                         (__attribute__((address_space(3))) void*)(lds + G * 16), 16, 0, 0);
    }
}

template <bool RELU, bool DUAL, bool OUT_F32>
__global__ __launch_bounds__(256) void mfma_gemm(const __bf16* __restrict__ A1, const __bf16* __restrict__ B1t, int K1,
                                                 const __bf16* __restrict__ A2, const __bf16* __restrict__ B2t, int K2,
                                                 const float* __restrict__ bias, void* __restrict__ Cout,
                                                 int M, int N) {
    __shared__ alignas(16) char lds[24576];  // A: 128x64 bf16 = 16 KB, B: 64x64 bf16 = 8 KB
    char* As = lds;
    char* Bs = lds + 16384;
    const int lane = threadIdx.x & 63, wid = threadIdx.x >> 6;
    const int wm = wid >> 1, wn = wid & 1;
    const int row0 = blockIdx.x * 128, col0 = blockIdx.y * 64;
    const int kg = lane >> 4, l15 = lane & 15;

    f32x4 acc[4][2];
#pragma unroll
    for (int mi = 0; mi < 4; ++mi)
#pragma unroll
        for (int ni = 0; ni < 2; ++ni) acc[mi][ni] = {0.f, 0.f, 0.f, 0.f};

    auto run_K = [&](const __bf16* A, const __bf16* Bt, int K) {
        for (int k0 = 0; k0 < K; k0 += 64) {
            stage_tile<128>(A, K, row0, M - 1, k0, As);
            stage_tile<64>(Bt, K, col0, N - 1, k0, Bs);
            __syncthreads();
            bf16x8 af[4][2], bfr[2][2];
#pragma unroll
            for (int mi = 0; mi < 4; ++mi) {
                int r = wm * 64 + mi * 16 + l15;
#pragma unroll
                for (int kf = 0; kf < 2; ++kf) {
                    int slot = (kf * 4 + kg) ^ (r & 7);
                    af[mi][kf] = *(const bf16x8*)(As + r * 128 + slot * 16);
                }
            }
#pragma unroll
            for (int ni = 0; ni < 2; ++ni) {
                int r = wn * 32 + ni * 16 + l15;
#pragma unroll
                for (int kf = 0; kf < 2; ++kf) {
                    int slot = (kf * 4 + kg) ^ (r & 7);
                    bfr[ni][kf] = *(const bf16x8*)(Bs + r * 128 + slot * 16);
                }
            }
#pragma unroll
            for (int mi = 0; mi < 4; ++mi)
#pragma unroll
                for (int ni = 0; ni < 2; ++ni)
#pragma unroll
                    for (int kf = 0; kf < 2; ++kf)
                        acc[mi][ni] = __builtin_amdgcn_mfma_f32_16x16x32_bf16(af[mi][kf], bfr[ni][kf],
                                                                              acc[mi][ni], 0, 0, 0);
            __syncthreads();
        }
    };
    run_K(A1, B1t, K1);
    if constexpr (DUAL) run_K(A2, B2t, K2);

    // epilogue: C/D layout col=lane&15, row=(lane>>4)*4+q  [m89]
#pragma unroll
    for (int mi = 0; mi < 4; ++mi) {
#pragma unroll
        for (int ni = 0; ni < 2; ++ni) {
            int col = col0 + wn * 32 + ni * 16 + l15;
            float bv = bias[col];
#pragma unroll
            for (int q = 0; q < 4; ++q) {
                int gr = row0 + wm * 64 + mi * 16 + kg * 4 + q;
                if (gr < M) {
                    float v = acc[mi][ni][q] + bv;
                    if (RELU) v = fmaxf(v, 0.f);
                    if (OUT_F32)
                        ((float*)Cout)[(size_t)gr * N + col] = v;
                    else
                        ((__bf16*)Cout)[(size_t)gr * N + col] = (__bf16)v;
                }
            }
        }
    }
}

// ---------------- launch ----------------

extern "C" void kernel_launch(void* const* d_in, const int* in_sizes, int n_in,
                              void* d_out, int out_size, void* d_ws, size_t ws_size,
                              hipStream_t stream) {
    const float* x  = (const float*)d_in[0];
    const int*   ei = (const int*)d_in[1];
    const int*   src = ei;
    const int*   dst = ei + N_EDGES;
    const float* W1 = (const float*)d_in[2];
    const float* b1 = (const float*)d_in[3];
    const float* W2 = (const float*)d_in[4];
    const float* b2 = (const float*)d_in[5];
    const float* Wf = (const float*)d_in[6];
    const float* bf = (const float*)d_in[7];
    const float* Ws = (const float*)d_in[8];
    const float* bs = (const float*)d_in[9];
    float* out = (float*)d_out;

    char* ws = (char*)d_ws;
    size_t off = 0;
    auto alloc = [&](size_t bytes) -> void* {
        void* p = ws + off;
        off += (bytes + 255) & ~(size_t)255;
        return p;
    };
    int*     deg      = (int*)alloc(N_NODES * 4);
    int*     cursor   = (int*)alloc(N_NODES * 4);
    int*     rowptr   = (int*)alloc((N_NODES + 1) * 4);
    float*   dinv     = (float*)alloc(N_NODES * 4);
    int*     blocksum = (int*)alloc(4096);
    int*     blockoff = (int*)alloc(4096);
    int*     csr      = (int*)alloc(N_EDGES * 4);
    __bf16*  x_bf     = (__bf16*)alloc((size_t)N_NODES * 128 * 2);
    __bf16*  W1t      = (__bf16*)alloc(128 * 256 * 2);
    __bf16*  W2t      = (__bf16*)alloc(256 * 256 * 2);
    __bf16*  Wft      = (__bf16*)alloc(256 * 64 * 2);
    __bf16*  Wst      = (__bf16*)alloc(128 * 64 * 2);
    float*   bfinal   = (float*)alloc(64 * 4);
    __bf16*  bufP1    = (__bf16*)alloc((size_t)N_NODES * 256 * 2);  // agg1 (128-wide), later h2
    __bf16*  bufP2    = (__bf16*)alloc((size_t)N_NODES * 256 * 2);  // h1
    __bf16*  bufP3    = (__bf16*)alloc((size_t)N_NODES * 256 * 2);  // agg2

    hipMemsetAsync(deg, 0, N_NODES * 4, stream);
    hipMemsetAsync(cursor, 0, N_NODES * 4, stream);

    hist_kernel<<<(N_EDGES + 255) / 256, 256, 0, stream>>>(dst, deg, N_EDGES);
    dinv_kernel<<<(N_NODES + 255) / 256, 256, 0, stream>>>(deg, dinv, N_NODES);

    int nb = (N_NODES + 511) / 512;  // 98
    scan_partial<<<nb, 512, 0, stream>>>(deg, N_NODES, rowptr, blocksum);
    scan_small<<<1, 128, 0, stream>>>(blocksum, nb, blockoff);
    scan_add<<<nb, 512, 0, stream>>>(rowptr, N_NODES, blockoff, N_EDGES);
    fill_csr<<<(N_EDGES + 255) / 256, 256, 0, stream>>>(src, dst, N_EDGES, rowptr, cursor, csr);

    // casts + weight prep
    cast_bf16_kernel<<<(N_NODES * 128 / 4 + 255) / 256, 256, 0, stream>>>(x, x_bf, N_NODES * 128 / 4);
    transpose_cast_kernel<<<(128 * 256 + 255) / 256, 256, 0, stream>>>(W1, W1t, 128, 256);
    transpose_cast_kernel<<<(256 * 256 + 255) / 256, 256, 0, stream>>>(W2, W2t, 256, 256);
    transpose_cast_kernel<<<(256 * 64 + 255) / 256, 256, 0, stream>>>(Wf, Wft, 256, 64);
    transpose_cast_kernel<<<(128 * 64 + 255) / 256, 256, 0, stream>>>(Ws, Wst, 128, 64);
    bias_add_kernel<<<1, 64, 0, stream>>>(bf, bs, bfinal, 64);

    const int gm = (N_NODES + 127) / 128;  // 391

    // layer 1: agg1 = Ahat x_bf (128-wide); h1 = relu(agg1 @ W1 + b1)
    aggregate_bf<128><<<(N_NODES + 3) / 4, 256, 0, stream>>>(x_bf, bufP1, rowptr, csr, dinv);
    mfma_gemm<true, false, false><<<dim3(gm, 4), 256, 0, stream>>>(bufP1, W1t, 128, nullptr, nullptr, 0,
                                                                   b1, bufP2, N_NODES, 256);
    // layer 2: agg2 = Ahat h1 (256-wide); h2 = relu(agg2 @ W2 + b2)
    aggregate_bf<256><<<(N_NODES + 3) / 4, 256, 0, stream>>>(bufP2, bufP3, rowptr, csr, dinv);
    mfma_gemm<true, false, false><<<dim3(gm, 4), 256, 0, stream>>>(bufP3, W2t, 256, nullptr, nullptr, 0,
                                                                   b2, bufP1, N_NODES, 256);
    // out = h2 @ Wf + x @ Ws + (bf + bs)
    mfma_gemm<false, true, true><<<dim3(gm, 1), 256, 0, stream>>>(bufP1, Wft, 256, x_bf, Wst, 128,
                                                                  bfinal, out, N_NODES, 64);
}

// Round 3
// 259.220 us; speedup vs baseline: 2.3786x; 1.3248x over previous
//
#include <hip/hip_runtime.h>

#define N_NODES 50000
#define N_EDGES 800000

typedef float f32x4 __attribute__((ext_vector_type(4)));
typedef __bf16 bf16x8 __attribute__((ext_vector_type(8)));
typedef __bf16 bf16x4 __attribute__((ext_vector_type(4)));
typedef __bf16 bf16x2 __attribute__((ext_vector_type(2)));

// ---------------- graph preprocessing ----------------

__global__ void hist_kernel(const int* __restrict__ dst, int* __restrict__ deg, int E) {
    int e = blockIdx.x * blockDim.x + threadIdx.x;
    if (e < E) atomicAdd(&deg[dst[e]], 1);
}

__global__ void dinv_kernel(const int* __restrict__ deg, float* __restrict__ dinv, int n) {
    int i = blockIdx.x * blockDim.x + threadIdx.x;
    if (i < n) dinv[i] = rsqrtf((float)(deg[i] + 1));  // +1 self-loop
}

__device__ __forceinline__ int wave_incl_scan(int x) {
    int lane = threadIdx.x & 63;
#pragma unroll
    for (int off = 1; off < 64; off <<= 1) {
        int y = __shfl_up(x, off, 64);
        if (lane >= off) x += y;
    }
    return x;
}

__global__ void scan_partial(const int* __restrict__ in, int n,
                             int* __restrict__ out_partial, int* __restrict__ blocksum) {
    __shared__ int wsum[8];
    int i = blockIdx.x * 512 + threadIdx.x;
    int v = (i < n) ? in[i] : 0;
    int inc = wave_incl_scan(v);
    int lane = threadIdx.x & 63, wid = threadIdx.x >> 6;
    if (lane == 63) wsum[wid] = inc;
    __syncthreads();
    if (wid == 0) {
        int w = (lane < 8) ? wsum[lane] : 0;
        int wi = wave_incl_scan(w);
        if (lane < 8) wsum[lane] = wi;
    }
    __syncthreads();
    int woff = (wid == 0) ? 0 : wsum[wid - 1];
    if (i < n) out_partial[i] = woff + inc - v;
    if (threadIdx.x == 0) blocksum[blockIdx.x] = wsum[7];
}

__global__ void scan_small(const int* __restrict__ in, int nb, int* __restrict__ out) {
    __shared__ int wsum[2];
    int i = threadIdx.x;
    int v = (i < nb) ? in[i] : 0;
    int inc = wave_incl_scan(v);
    int lane = threadIdx.x & 63, wid = threadIdx.x >> 6;
    if (lane == 63) wsum[wid] = inc;
    __syncthreads();
    int woff = (wid == 0) ? 0 : wsum[0];
    if (i < nb) out[i] = woff + inc - v;
}

__global__ void scan_add(int* __restrict__ rowptr, int n, const int* __restrict__ blockoff, int total) {
    int i = blockIdx.x * 512 + threadIdx.x;
    if (i < n) rowptr[i] += blockoff[blockIdx.x];
    if (i == 0) rowptr[n] = total;
}

__global__ void fill_csr(const int* __restrict__ src, const int* __restrict__ dst, int E,
                         const int* __restrict__ rowptr, int* __restrict__ cursor,
                         int* __restrict__ csr_src) {
    int e = blockIdx.x * blockDim.x + threadIdx.x;
    if (e < E) {
        int d = dst[e];
        int pos = rowptr[d] + atomicAdd(&cursor[d], 1);
        csr_src[pos] = src[e];
    }
}

// ---------------- casts / weight prep ----------------

// writes x_bf (unscaled) and x_s (row-scaled by dinv) in one pass
__global__ void cast_scale_kernel(const float* __restrict__ in, const float* __restrict__ dinv,
                                  __bf16* __restrict__ x_bf, __bf16* __restrict__ x_s, int n4) {
    int i = blockIdx.x * blockDim.x + threadIdx.x;
    if (i < n4) {
        float4 v = ((const float4*)in)[i];
        float di = dinv[i >> 5];  // 32 float4 per 128-wide row
        bf16x4 a = {(__bf16)v.x, (__bf16)v.y, (__bf16)v.z, (__bf16)v.w};
        bf16x4 s = {(__bf16)(di * v.x), (__bf16)(di * v.y), (__bf16)(di * v.z), (__bf16)(di * v.w)};
        ((bf16x4*)x_bf)[i] = a;
        ((bf16x4*)x_s)[i] = s;
    }
}

// Wt[n*K + k] = (bf16) W[k*N + n]
__global__ void transpose_cast_kernel(const float* __restrict__ W, __bf16* __restrict__ Wt, int K, int N) {
    int idx = blockIdx.x * blockDim.x + threadIdx.x;
    if (idx < K * N) {
        int n = idx / K, k = idx - n * K;
        Wt[idx] = (__bf16)W[(size_t)k * N + n];
    }
}

__global__ void bias_add_kernel(const float* __restrict__ a, const float* __restrict__ b,
                                float* __restrict__ o, int n) {
    int i = blockIdx.x * blockDim.x + threadIdx.x;
    if (i < n) o[i] = a[i] + b[i];
}

// ---------------- aggregation: out[i] = dinv[i]*(in_s[i] + sum_e in_s[s]) ----------------
// in_s is pre-scaled by dinv (self-loop term included). One wave per node; edge loop
// unrolled 4x for 4 independent gathers in flight (latency-bound fix).

template <int V> struct VecSel;
template <> struct VecSel<2> { using T = bf16x2; };
template <> struct VecSel<4> { using T = bf16x4; };

template <int F>
__global__ __launch_bounds__(256) void aggregate_sum(const __bf16* __restrict__ in_s, __bf16* __restrict__ out,
                                                     const int* __restrict__ rowptr, const int* __restrict__ csr_src,
                                                     const float* __restrict__ dinv) {
    constexpr int V = F / 64;
    using VT = typename VecSel<V>::T;
    int node = blockIdx.x * 4 + (threadIdx.x >> 6);
    if (node >= N_NODES) return;
    int lane = threadIdx.x & 63;
    const __bf16* base = in_s + (size_t)lane * V;
    VT sv = *(const VT*)(base + (size_t)node * F);
    float acc[V];
#pragma unroll
    for (int j = 0; j < V; ++j) acc[j] = (float)sv[j];
    int beg = rowptr[node], end = rowptr[node + 1];
    int e = beg;
    for (; e + 4 <= end; e += 4) {
        int s0 = csr_src[e + 0], s1 = csr_src[e + 1], s2 = csr_src[e + 2], s3 = csr_src[e + 3];
        VT v0 = *(const VT*)(base + (size_t)s0 * F);
        VT v1 = *(const VT*)(base + (size_t)s1 * F);
        VT v2 = *(const VT*)(base + (size_t)s2 * F);
        VT v3 = *(const VT*)(base + (size_t)s3 * F);
#pragma unroll
        for (int j = 0; j < V; ++j) {
            acc[j] += (float)v0[j];
            acc[j] += (float)v1[j];
            acc[j] += (float)v2[j];
            acc[j] += (float)v3[j];
        }
    }
    for (; e < end; ++e) {
        int s = csr_src[e];
        VT v = *(const VT*)(base + (size_t)s * F);
#pragma unroll
        for (int j = 0; j < V; ++j) acc[j] += (float)v[j];
    }
    float di = dinv[node];
    VT o;
#pragma unroll
    for (int j = 0; j < V; ++j) o[j] = (__bf16)(di * acc[j]);
    *(VT*)(out + (size_t)node * F + lane * V) = o;
}

// ---------------- MFMA bf16 GEMM staging (shared) ----------------
// LDS rows of 64 bf16 (8 x 16B granules), granule slot XOR-swizzled with (row&7).
// global_load_lds writes linearly; global SOURCE address pre-swizzled with the same
// involution so the swizzled read matches (rule 21).

template <int NROWS, int NTH>
__device__ __forceinline__ void stage_tile(const __bf16* __restrict__ src, int K, int row0, int rowclamp,
                                           int k0, char* lds) {
    int t = threadIdx.x;
#pragma unroll
    for (int p = 0; p < NROWS * 8 / NTH; ++p) {
        int G = p * NTH + t;
        int r = G >> 3, gp = G & 7;
        int g = gp ^ (r & 7);
        int gr = row0 + r;
        if (gr > rowclamp) gr = rowclamp;
        const __bf16* sp = src + (size_t)gr * K + k0 + g * 8;
        __builtin_amdgcn_global_load_lds((const __attribute__((address_space(1))) void*)sp,
                                         (__attribute__((address_space(3))) void*)(lds + G * 16), 16, 0, 0);
    }
}

// ---------------- wide GEMM: C[M x 256] = A[M x K] * Bt[256 x K]^T, BM=128, 8 waves ----------------

template <bool SCALE>
__global__ __launch_bounds__(512) void mfma_gemm_wide(const __bf16* __restrict__ A, const __bf16* __restrict__ Bt,
                                                      int K, const float* __restrict__ bias,
                                                      const float* __restrict__ dinv,
                                                      __bf16* __restrict__ C, int M) {
    constexpr int N = 256;
    __shared__ alignas(16) char lds[49152];  // A: 128x64 = 16 KB, B: 256x64 = 32 KB
    char* As = lds;
    char* Bs = lds + 16384;
    const int lane = threadIdx.x & 63, wid = threadIdx.x >> 6;
    const int wm = wid >> 2, wn = wid & 3;  // 2 x 4 waves, wave tile 64x64
    const int row0 = blockIdx.x * 128;
    const int kg = lane >> 4, l15 = lane & 15;

    f32x4 acc[4][4];
#pragma unroll
    for (int mi = 0; mi < 4; ++mi)
#pragma unroll
        for (int ni = 0; ni < 4; ++ni) acc[mi][ni] = {0.f, 0.f, 0.f, 0.f};

    for (int k0 = 0; k0 < K; k0 += 64) {
        stage_tile<128, 512>(A, K, row0, M - 1, k0, As);
        stage_tile<256, 512>(Bt, K, 0, N - 1, k0, Bs);
        __syncthreads();
        bf16x8 af[4][2], bfr[4][2];
#pragma unroll
        for (int mi = 0; mi < 4; ++mi) {
            int r = wm * 64 + mi * 16 + l15;
#pragma unroll
            for (int kf = 0; kf < 2; ++kf) {
                int slot = (kf * 4 + kg) ^ (r & 7);
                af[mi][kf] = *(const bf16x8*)(As + r * 128 + slot * 16);
            }
        }
#pragma unroll
        for (int ni = 0; ni < 4; ++ni) {
            int r = wn * 64 + ni * 16 + l15;
#pragma unroll
            for (int kf = 0; kf < 2; ++kf) {
                int slot = (kf * 4 + kg) ^ (r & 7);
                bfr[ni][kf] = *(const bf16x8*)(Bs + r * 128 + slot * 16);
            }
        }
#pragma unroll
        for (int mi = 0; mi < 4; ++mi)
#pragma unroll
            for (int ni = 0; ni < 4; ++ni)
#pragma unroll
                for (int kf = 0; kf < 2; ++kf)
                    acc[mi][ni] = __builtin_amdgcn_mfma_f32_16x16x32_bf16(af[mi][kf], bfr[ni][kf],
                                                                          acc[mi][ni], 0, 0, 0);
        __syncthreads();
    }

    // C/D layout: col = lane&15, row = (lane>>4)*4 + q
#pragma unroll
    for (int mi = 0; mi < 4; ++mi) {
#pragma unroll
        for (int q = 0; q < 4; ++q) {
            int gr = row0 + wm * 64 + mi * 16 + kg * 4 + q;
            if (gr >= M) continue;
            float sc = SCALE ? dinv[gr] : 1.0f;
#pragma unroll
            for (int ni = 0; ni < 4; ++ni) {
                int col = wn * 64 + ni * 16 + l15;
                float v = acc[mi][ni][q] + bias[col];
                v = fmaxf(v, 0.f);  // both uses are relu layers
                if (SCALE) v *= sc;
                C[(size_t)gr * N + col] = (__bf16)v;
            }
        }
    }
}

// ---------------- final GEMM: out[M x 64] = A1*B1t^T + A2*B2t^T + bias (f32 out) ----------------
// BM=128, BN=64, 4 waves (2x2), wave tile 64x32.

__global__ __launch_bounds__(256) void mfma_gemm_final(const __bf16* __restrict__ A1, const __bf16* __restrict__ B1t, int K1,
                                                       const __bf16* __restrict__ A2, const __bf16* __restrict__ B2t, int K2,
                                                       const float* __restrict__ bias, float* __restrict__ Cout, int M) {
    constexpr int N = 64;
    __shared__ alignas(16) char lds[24576];
    char* As = lds;
    char* Bs = lds + 16384;
    const int lane = threadIdx.x & 63, wid = threadIdx.x >> 6;
    const int wm = wid >> 1, wn = wid & 1;
    const int row0 = blockIdx.x * 128;
    const int kg = lane >> 4, l15 = lane & 15;

    f32x4 acc[4][2];
#pragma unroll
    for (int mi = 0; mi < 4; ++mi)
#pragma unroll
        for (int ni = 0; ni < 2; ++ni) acc[mi][ni] = {0.f, 0.f, 0.f, 0.f};

    auto run_K = [&](const __bf16* A, const __bf16* Bt, int K) {
        for (int k0 = 0; k0 < K; k0 += 64) {
            stage_tile<128, 256>(A, K, row0, M - 1, k0, As);
            stage_tile<64, 256>(Bt, K, 0, N - 1, k0, Bs);
            __syncthreads();
            bf16x8 af[4][2], bfr[2][2];
#pragma unroll
            for (int mi = 0; mi < 4; ++mi) {
                int r = wm * 64 + mi * 16 + l15;
#pragma unroll
                for (int kf = 0; kf < 2; ++kf) {
                    int slot = (kf * 4 + kg) ^ (r & 7);
                    af[mi][kf] = *(const bf16x8*)(As + r * 128 + slot * 16);
                }
            }
#pragma unroll
            for (int ni = 0; ni < 2; ++ni) {
                int r = wn * 32 + ni * 16 + l15;
#pragma unroll
                for (int kf = 0; kf < 2; ++kf) {
                    int slot = (kf * 4 + kg) ^ (r & 7);
                    bfr[ni][kf] = *(const bf16x8*)(Bs + r * 128 + slot * 16);
                }
            }
#pragma unroll
            for (int mi = 0; mi < 4; ++mi)
#pragma unroll
                for (int ni = 0; ni < 2; ++ni)
#pragma unroll
                    for (int kf = 0; kf < 2; ++kf)
                        acc[mi][ni] = __builtin_amdgcn_mfma_f32_16x16x32_bf16(af[mi][kf], bfr[ni][kf],
                                                                              acc[mi][ni], 0, 0, 0);
            __syncthreads();
        }
    };
    run_K(A1, B1t, K1);
    run_K(A2, B2t, K2);

#pragma unroll
    for (int mi = 0; mi < 4; ++mi) {
#pragma unroll
        for (int ni = 0; ni < 2; ++ni) {
            int col = wn * 32 + ni * 16 + l15;
            float bv = bias[col];
#pragma unroll
            for (int q = 0; q < 4; ++q) {
                int gr = row0 + wm * 64 + mi * 16 + kg * 4 + q;
                if (gr < M) Cout[(size_t)gr * N + col] = acc[mi][ni][q] + bv;
            }
        }
    }
}

// ---------------- launch ----------------

extern "C" void kernel_launch(void* const* d_in, const int* in_sizes, int n_in,
                              void* d_out, int out_size, void* d_ws, size_t ws_size,
                              hipStream_t stream) {
    const float* x  = (const float*)d_in[0];
    const int*   ei = (const int*)d_in[1];
    const int*   src = ei;
    const int*   dst = ei + N_EDGES;
    const float* W1 = (const float*)d_in[2];
    const float* b1 = (const float*)d_in[3];
    const float* W2 = (const float*)d_in[4];
    const float* b2 = (const float*)d_in[5];
    const float* Wf = (const float*)d_in[6];
    const float* bf = (const float*)d_in[7];
    const float* Ws = (const float*)d_in[8];
    const float* bs = (const float*)d_in[9];
    float* out = (float*)d_out;

    char* ws = (char*)d_ws;
    size_t off = 0;
    auto alloc = [&](size_t bytes) -> void* {
        void* p = ws + off;
        off += (bytes + 255) & ~(size_t)255;
        return p;
    };
    int*     deg      = (int*)alloc(N_NODES * 4);
    int*     cursor   = (int*)alloc(N_NODES * 4);
    int*     rowptr   = (int*)alloc((N_NODES + 1) * 4);
    float*   dinv     = (float*)alloc(N_NODES * 4);
    int*     blocksum = (int*)alloc(4096);
    int*     blockoff = (int*)alloc(4096);
    int*     csr      = (int*)alloc(N_EDGES * 4);
    __bf16*  x_bf     = (__bf16*)alloc((size_t)N_NODES * 128 * 2);  // unscaled (skip GEMM)
    __bf16*  x_s      = (__bf16*)alloc((size_t)N_NODES * 128 * 2);  // dinv-scaled (agg1 input)
    __bf16*  W1t      = (__bf16*)alloc(128 * 256 * 2);
    __bf16*  W2t      = (__bf16*)alloc(256 * 256 * 2);
    __bf16*  Wft      = (__bf16*)alloc(256 * 64 * 2);
    __bf16*  Wst      = (__bf16*)alloc(128 * 64 * 2);
    float*   bfinal   = (float*)alloc(64 * 4);
    __bf16*  bufP1    = (__bf16*)alloc((size_t)N_NODES * 256 * 2);  // agg1 out (128-wide), later h2
    __bf16*  bufP2    = (__bf16*)alloc((size_t)N_NODES * 256 * 2);  // h1_s
    __bf16*  bufP3    = (__bf16*)alloc((size_t)N_NODES * 256 * 2);  // agg2 out

    hipMemsetAsync(deg, 0, N_NODES * 4, stream);
    hipMemsetAsync(cursor, 0, N_NODES * 4, stream);

    hist_kernel<<<(N_EDGES + 255) / 256, 256, 0, stream>>>(dst, deg, N_EDGES);
    dinv_kernel<<<(N_NODES + 255) / 256, 256, 0, stream>>>(deg, dinv, N_NODES);

    int nb = (N_NODES + 511) / 512;  // 98
    scan_partial<<<nb, 512, 0, stream>>>(deg, N_NODES, rowptr, blocksum);
    scan_small<<<1, 128, 0, stream>>>(blocksum, nb, blockoff);
    scan_add<<<nb, 512, 0, stream>>>(rowptr, N_NODES, blockoff, N_EDGES);
    fill_csr<<<(N_EDGES + 255) / 256, 256, 0, stream>>>(src, dst, N_EDGES, rowptr, cursor, csr);

    cast_scale_kernel<<<(N_NODES * 128 / 4 + 255) / 256, 256, 0, stream>>>(x, dinv, x_bf, x_s, N_NODES * 128 / 4);
    transpose_cast_kernel<<<(128 * 256 + 255) / 256, 256, 0, stream>>>(W1, W1t, 128, 256);
    transpose_cast_kernel<<<(256 * 256 + 255) / 256, 256, 0, stream>>>(W2, W2t, 256, 256);
    transpose_cast_kernel<<<(256 * 64 + 255) / 256, 256, 0, stream>>>(Wf, Wft, 256, 64);
    transpose_cast_kernel<<<(128 * 64 + 255) / 256, 256, 0, stream>>>(Ws, Wst, 128, 64);
    bias_add_kernel<<<1, 64, 0, stream>>>(bf, bs, bfinal, 64);

    const int gm = (N_NODES + 127) / 128;  // 391

    // layer 1: agg1 = Ahat x (via pre-scaled x_s); h1_s = dinv * relu(agg1 @ W1 + b1)
    aggregate_sum<128><<<(N_NODES + 3) / 4, 256, 0, stream>>>(x_s, bufP1, rowptr, csr, dinv);
    mfma_gemm_wide<true><<<gm, 512, 0, stream>>>(bufP1, W1t, 128, b1, dinv, bufP2, N_NODES);

    // layer 2: agg2 = sum of h1_s (+ self) * dinv; h2 = relu(agg2 @ W2 + b2)
    aggregate_sum<256><<<(N_NODES + 3) / 4, 256, 0, stream>>>(bufP2, bufP3, rowptr, csr, dinv);
    mfma_gemm_wide<false><<<gm, 512, 0, stream>>>(bufP3, W2t, 256, b2, nullptr, bufP1, N_NODES);

    // out = h2 @ Wf + x @ Ws + (bf + bs)
    mfma_gemm_final<<<gm, 256, 0, stream>>>(bufP1, Wft, 256, x_bf, Wst, 128, bfinal, out, N_NODES);
}